// Round 14
// baseline (30.160 us; speedup 1.0000x reference)
//
#include <hip/hip_runtime.h>

constexpr int KWIN = 100;
constexpr int HK   = 50;
constexpr int TSUB = 64;    // frames per thread (16 main batches of 4)
constexpr int MB   = 4;     // incoming loads per batch (A/B pipelined)
constexpr int PB   = 20;    // prime batch -> 5 batches into ring slots

template <bool REFLECT>
__device__ __forceinline__ int tidx(int t) {
    if constexpr (REFLECT) {
        constexpr int T = 16384;
        t = (t < 0) ? -t : t;
        return (t >= T) ? (2 * T - 2 - t) : t;
    }
    return t;   // interior chunk: linear addressing
}

template <bool REFLECT>
__device__ __forceinline__ void run_chunk(
    const float* __restrict__ xb, float* __restrict__ ob, const int t0)
{
    // slot s holds frame t0-50+s after prime; after step k's refill,
    // slot k%100 holds frame t0+k+50. All indices compile-time static.
    float ring[KWIN];
    float sx = 0.f, sq = 0.f;

    // ---- prime: 5 batches of 20 loads directly into ring slots,
    // accumulation of batch k overlapped with loads of batch k+1 ----
#define PLOAD(KB)                                                             \
    {                                                                         \
        _Pragma("unroll")                                                     \
        for (int j = 0; j < PB; ++j)                                          \
            ring[(KB) * PB + j] =                                             \
                xb[(size_t)tidx<REFLECT>(t0 - HK + (KB) * PB + j) * 128];     \
    }
#define PACC(KB)                                                              \
    {                                                                         \
        _Pragma("unroll")                                                     \
        for (int j = 0; j < PB; ++j) {                                        \
            const float u = ring[(KB) * PB + j];                              \
            sx += u;                                                          \
            sq  = fmaf(u, u, sq);                                             \
        }                                                                     \
    }
    PLOAD(0); PLOAD(1);
    PACC(0);  PLOAD(2);
    PACC(1);  PLOAD(3);
    PACC(2);  PLOAD(4);
    PACC(3);
    PACC(4);
#undef PLOAD
#undef PACC

    const float invK   = 1.0f / (float)KWIN;
    const float invKm1 = 1.0f / (float)(KWIN - 1);
    const float fK     = (float)KWIN;

    // ---- main: 16 batches of 4 outputs, 2-deep A/B pipeline.
    // Only ONE load per output (incoming x[t+50]); center and outgoing
    // both come from the register ring.
    float inA[MB], inB[MB];

#define LOADB(IN, KB)                                                         \
    {                                                                         \
        _Pragma("unroll")                                                     \
        for (int j = 0; j < MB; ++j)                                          \
            IN[j] = xb[(size_t)tidx<REFLECT>(t0 + (KB) + j + HK) * 128];      \
    }
#define COMPUTEB(IN, KB)                                                      \
    {                                                                         \
        _Pragma("unroll")                                                     \
        for (int j = 0; j < MB; ++j) {                                        \
            const int k = (KB) + j;                                           \
            const float c  = ring[(k + HK) % KWIN];   /* frame t0+k   */      \
            const float o  = ring[k % KWIN];          /* frame t0+k-50*/      \
            const float m  = sx * invK;                                       \
            const float va = fmaxf((sq - fK * m * m) * invKm1, 1e-24f);       \
            const float rs = __builtin_amdgcn_rsqf(va);                       \
            __builtin_nontemporal_store((c - m) * rs,                         \
                                        &ob[(size_t)(t0 + k) * 128]);         \
            sx += IN[j] - o;                                                  \
            sq += IN[j] * IN[j] - o * o;                                      \
            ring[k % KWIN] = IN[j];                                           \
        }                                                                     \
    }

    LOADB(inA, 0 * MB);
    LOADB(inB, 1 * MB);
    COMPUTEB(inA, 0 * MB);  LOADB(inA, 2 * MB);
    COMPUTEB(inB, 1 * MB);  LOADB(inB, 3 * MB);
    COMPUTEB(inA, 2 * MB);  LOADB(inA, 4 * MB);
    COMPUTEB(inB, 3 * MB);  LOADB(inB, 5 * MB);
    COMPUTEB(inA, 4 * MB);  LOADB(inA, 6 * MB);
    COMPUTEB(inB, 5 * MB);  LOADB(inB, 7 * MB);
    COMPUTEB(inA, 6 * MB);  LOADB(inA, 8 * MB);
    COMPUTEB(inB, 7 * MB);  LOADB(inB, 9 * MB);
    COMPUTEB(inA, 8 * MB);  LOADB(inA, 10 * MB);
    COMPUTEB(inB, 9 * MB);  LOADB(inB, 11 * MB);
    COMPUTEB(inA, 10 * MB); LOADB(inA, 12 * MB);
    COMPUTEB(inB, 11 * MB); LOADB(inB, 13 * MB);
    COMPUTEB(inA, 12 * MB); LOADB(inA, 14 * MB);
    COMPUTEB(inB, 13 * MB); LOADB(inB, 15 * MB);
    COMPUTEB(inA, 14 * MB);
    COMPUTEB(inB, 15 * MB);

#undef LOADB
#undef COMPUTEB
}

__global__ __launch_bounds__(256, 2) void man_kernel(
    const float* __restrict__ x, float* __restrict__ out)
{
    constexpr int T = 16384, D = 128;

    const int i   = blockIdx.x;                  // 0..1023
    const int bb  = (i & 7) * 128 + (i >> 3);    // XCD (i&7) owns batch b
    const int b   = bb >> 7;                     // 0..7
    const int seg = bb & 127;                    // pair of adjacent chunks
    const int w   = threadIdx.x >> 7;            // 0..1 chunk within pair
    const int tid = threadIdx.x & 127;           // d column
    const int t0  = (seg * 2 + w) * TSUB;

    const float* __restrict__ xb = x   + (size_t)b * T * D + tid;
    float*       __restrict__ ob = out + (size_t)b * T * D + tid;

    if (t0 >= HK && t0 + TSUB - 1 + HK < T) {
        run_chunk<false>(xb, ob, t0);
    } else {
        run_chunk<true>(xb, ob, t0);
    }
}

extern "C" void kernel_launch(void* const* d_in, const int* in_sizes, int n_in,
                              void* d_out, int out_size, void* d_ws, size_t ws_size,
                              hipStream_t stream) {
    (void)in_sizes; (void)n_in; (void)d_ws; (void)ws_size; (void)out_size;
    const float* x = (const float*)d_in[0];
    float* out = (float*)d_out;
    // 8 b * 256 chunks * 128 d = 262144 threads = 1024 blocks * 256
    man_kernel<<<dim3(1024), dim3(256), 0, stream>>>(x, out);
}